// Round 9
// baseline (239.006 us; speedup 1.0000x reference)
//
#include <hip/hip_runtime.h>

constexpr int Bn = 8, Cn = 3, Hn = 720, Wn = 1280;
constexpr int HW = Hn * Wn;                    // 921600 px per image
constexpr long long NTOT = (long long)Bn * Cn * HW;

constexpr int BLK   = 256;
constexpr int NBX   = 512;                     // blocks per XCD (= per batch image)
constexpr int NWG   = 8 * NBX;                 // 4096 blocks = 16/CU
constexpr int SPI   = HW / BLK;                // 3600 strips per image (5 per row)
constexpr int WROWS = 8;                       // window rows: y-3 .. y+4
constexpr int WCOLS = 264;                     // window cols: xs-4 .. xs+259 (16B-aligned start)
constexpr int F4PP  = WROWS * WCOLS / 4;       // 528 float4 per plane
constexpr int F4ROW = WCOLS / 4;               // 66 float4 per row

typedef float f4 __attribute__((ext_vector_type(4)));

// Tap for one warp direction. Window semantics: LDS col j holds source col
// clamp(xs-4+j, 0, W-1); LDS row r holds source row clamp(y+r-3, 0, H-1).
// Border clamps therefore come free from staging duplication.
__device__ __forceinline__ void mk_tap(int x, int y, int xs, float fx, float fy,
                                       int& addr, float& wx, float& wy) {
    fx = fminf(fmaxf(fx, -4.0f), 3.99951171875f);   // keep x0 in [xs-4, xs+258]
    fy = fminf(fmaxf(fy, -3.0f), 3.99951171875f);   // keep y0 in [y-3,  y+3]
    const float xc = fminf(fmaxf((float)x + fx, 0.f), (float)(Wn - 1));
    const float yc = fminf(fmaxf((float)y + fy, 0.f), (float)(Hn - 1));
    const float x0f = floorf(xc), y0f = floorf(yc);
    wx = xc - x0f;  wy = yc - y0f;
    const int j0 = (int)x0f - xs + 4;              // [0, 262]
    const int r0 = (int)y0f - y + 3;               // [0, 6]
    addr = r0 * WCOLS + j0;
}

__device__ __forceinline__ float bilin_lds(const float* __restrict__ w,
                                           int a, float wx, float wy) {
    const float v00 = w[a],         v01 = w[a + 1];
    const float v10 = w[a + WCOLS], v11 = w[a + WCOLS + 1];
    const float top = fmaf(wx, v01 - v00, v00);
    const float bot = fmaf(wx, v11 - v10, v10);
    return fmaf(wy, bot - top, top);
}

__global__ __launch_bounds__(256, 8) void warp_loss_kernel(
        const float* __restrict__ L, const float* __restrict__ R,
        const float* __restrict__ Flm, const float* __restrict__ Frm,
        const float* __restrict__ G, double* __restrict__ accum) {
    // XCD k (= bid%8) owns batch image k; strips walked chunk-major so each
    // XCD sweeps a ~102-row band (~3.2MB of L,R planes) that fits its 4MB L2.
    const int b     = blockIdx.x & 7;
    const int inner = blockIdx.x >> 3;
    const int tid   = (int)threadIdx.x;

    const float* __restrict__ Lb = L + (size_t)b * Cn * HW;
    const float* __restrict__ Rb = R + (size_t)b * Cn * HW;
    const float* __restrict__ Gb = G + (size_t)b * Cn * HW;
    const float* __restrict__ fl = Flm + (size_t)b * 2 * HW;  // [0,HW)=x, [HW,2HW)=y
    const float* __restrict__ fr = Frm + (size_t)b * 2 * HW;

    __shared__ float win[2][WROWS][WCOLS];        // 16.9 KB: L_c and R_c windows

    float local = 0.f;

    for (int s = inner; s < SPI; s += NBX) {
        const int y  = s / 5;                     // 5 strips per image row
        const int xs = (s - y * 5) * BLK;
        const int p  = y * Wn + xs + tid;

        const float lfx = fl[p], lfy = fl[HW + p];
        const float rfx = fr[p], rfy = fr[HW + p];

        int aL, aR; float lwx, lwy, rwx, rwy;
        mk_tap(xs + tid, y, xs, lfx, lfy, aL, lwx, lwy);   // channel-invariant
        mk_tap(xs + tid, y, xs, rfx, rfy, aR, rwx, rwy);

        for (int c = 0; c < Cn; ++c) {
            __syncthreads();                      // prior gathers done before overwrite

            // stage L_c window (plane 0) and R_c window (plane 1): 1056 float4
            const float* __restrict__ Lc = Lb + (size_t)c * HW;
            const float* __restrict__ Rc = Rb + (size_t)c * HW;
            #pragma unroll
            for (int k = 0; k < 5; ++k) {
                const int idx = k * BLK + tid;
                if (idx < 2 * F4PP) {
                    const int  pl  = idx >= F4PP;
                    const int  f   = idx - pl * F4PP;
                    const int  row = f / F4ROW;
                    const int  c4  = f - row * F4ROW;
                    const int  xw  = xs - 4 + c4 * 4;              // multiple of 4
                    const int  ys  = min(max(y + row - 3, 0), Hn - 1);
                    const float* __restrict__ src = (pl ? Rc : Lc) + (size_t)ys * Wn;
                    f4 v;
                    if (xw < 0)            { const float e = src[0];      v = (f4){e, e, e, e}; }
                    else if (xw + 3 >= Wn) { const float e = src[Wn - 1]; v = (f4){e, e, e, e}; }
                    else                   { v = *reinterpret_cast<const f4*>(src + xw); }
                    *reinterpret_cast<f4*>(&win[pl][row][c4 * 4]) = v;
                }
            }
            __syncthreads();

            const float g  = Gb[c * HW + p];
            const float sL = bilin_lds(&win[0][0][0], aL, lwx, lwy);
            const float sR = bilin_lds(&win[1][0][0], aR, rwx, rwy);
            local += fabsf(sL - g) + fabsf(sR - g);
        }
    }

    // wave(64) shuffle reduce -> LDS cross-wave -> one f64 atomic per block
    #pragma unroll
    for (int off = 32; off > 0; off >>= 1)
        local += __shfl_down(local, off, 64);

    __shared__ float wsum[4];
    const int lane = tid & 63;
    const int wid  = tid >> 6;
    if (lane == 0) wsum[wid] = local;
    __syncthreads();
    if (tid == 0) {
        const float sum = wsum[0] + wsum[1] + wsum[2] + wsum[3];
        atomicAdd(accum, (double)sum);
    }
}

__global__ void finalize_kernel(const double* __restrict__ accum,
                                float* __restrict__ out) {
    out[0] = (float)(accum[0] / (double)NTOT);
}

extern "C" void kernel_launch(void* const* d_in, const int* in_sizes, int n_in,
                              void* d_out, int out_size, void* d_ws, size_t ws_size,
                              hipStream_t stream) {
    const float* L   = (const float*)d_in[0];
    const float* R   = (const float*)d_in[1];
    const float* flm = (const float*)d_in[2];
    const float* frm = (const float*)d_in[3];
    const float* gt  = (const float*)d_in[4];
    double* accum = (double*)d_ws;

    (void)hipMemsetAsync(accum, 0, sizeof(double), stream);
    warp_loss_kernel<<<NWG, BLK, 0, stream>>>(L, R, flm, frm, gt, accum);
    finalize_kernel<<<1, 1, 0, stream>>>(accum, (float*)d_out);
}

// Round 10
// 161.256 us; speedup vs baseline: 1.4822x; 1.4822x over previous
//
#include <hip/hip_runtime.h>

constexpr int Bn = 8, Cn = 3, Hn = 720, Wn = 1280;
constexpr int HW = Hn * Wn;                    // 921600 px per image
constexpr long long NTOT = (long long)Bn * Cn * HW;

constexpr int BLK    = 256;
constexpr int NBX    = 512;                    // blocks per XCD (= per batch image)
constexpr int NWG    = 8 * NBX;                // 4096 blocks = 16/CU (2 exact rounds of 8)
constexpr int CH     = NBX * BLK;              // 131072 px per chunk per image
constexpr int NCHUNK = (HW + CH - 1) / CH;     // 8 (7 full + 4096-px partial)

// 8B tap-pair; 4B-aligned (gfx950 handles dword-aligned dwordx2)
typedef float f2 __attribute__((ext_vector_type(2), aligned(4)));

// One gather address per row: o0 -> (y0, x0), o1 -> (y1, x0).
// x0 = min(floor(xc), W-2) keeps the 8B pair in-row; wx in [0,1] (wx=1 at border).
__device__ __forceinline__ void mk2(float xf, float yf,
                                    int& o0, int& o1, float& wx, float& wy) {
    xf = fminf(fmaxf(xf, 0.f), (float)(Wn - 1));
    yf = fminf(fmaxf(yf, 0.f), (float)(Hn - 1));
    const int x0 = min((int)floorf(xf), Wn - 2);
    wx = xf - (float)x0;
    const float y0f = floorf(yf);
    const int y0 = (int)y0f;
    const int y1 = min(y0 + 1, Hn - 1);
    wy = yf - y0f;
    o0 = y0 * Wn + x0;
    o1 = y1 * Wn + x0;
}

__global__ __launch_bounds__(256) void warp_loss_kernel(
        const float* __restrict__ L, const float* __restrict__ R,
        const float* __restrict__ Flm, const float* __restrict__ Frm,
        const float* __restrict__ G, double* __restrict__ accum) {
    // XCD k (= bid%8) owns batch image k. 512 blocks/XCD = 2 exact rounds of
    // the XCD's 256 block-slots (backfill absorbs finish-time skew).
    const int b     = blockIdx.x & 7;
    const int inner = blockIdx.x >> 3;

    const float* __restrict__ Lb = L + (size_t)b * Cn * HW;
    const float* __restrict__ Rb = R + (size_t)b * Cn * HW;
    const float* __restrict__ Gb = G + (size_t)b * Cn * HW;
    const float* __restrict__ fl = Flm + (size_t)b * 2 * HW;  // [0,HW)=x, [HW,2HW)=y
    const float* __restrict__ fr = Frm + (size_t)b * 2 * HW;

    float local = 0.f;

    const int p0 = inner * BLK + (int)threadIdx.x;   // [0, 131072)
    // software pipeline: flow for chunk 0 loaded up front (p0 < HW always)
    float lfx = fl[p0], lfy = fl[HW + p0];
    float rfx = fr[p0], rfy = fr[HW + p0];

    for (int chunk = 0; chunk < NCHUNK; ++chunk) {
        const int p     = p0 + chunk * CH;               // may exceed HW on last chunk
        const int p_nxt = min(p0 + (chunk + 1) * CH, HW - 1);  // clamped prefetch addr

        if (p < HW) {   // wave-uniform (p0 wave-contiguous, CH multiple of 64)
            const int y = p / Wn;
            const int x = p - y * Wn;

            int   lo0, lo1, ro0, ro1;
            float lwx, lwy, rwx, rwy;
            mk2((float)x + lfx, (float)y + lfy, lo0, lo1, lwx, lwy);
            mk2((float)x + rfx, (float)y + rfy, ro0, ro1, rwx, rwy);

            // ---- issue ALL 15 loads before any consumption (1 latency epoch,
            //      not 3): 12 gather dwordx2 + 3 gt dword into named regs ----
            f2 tl0[Cn], tl1[Cn], tr0[Cn], tr1[Cn];
            float g[Cn];
            #pragma unroll
            for (int c = 0; c < Cn; ++c) {
                const float* __restrict__ Lc = Lb + c * HW;
                const float* __restrict__ Rc = Rb + c * HW;
                tl0[c] = *reinterpret_cast<const f2*>(Lc + lo0);
                tl1[c] = *reinterpret_cast<const f2*>(Lc + lo1);
                tr0[c] = *reinterpret_cast<const f2*>(Rc + ro0);
                tr1[c] = *reinterpret_cast<const f2*>(Rc + ro1);
                g[c]   = Gb[c * HW + p];
            }

            // next chunk's flow loads issue behind the gathers (needed latest)
            const float nlfx = fl[p_nxt], nlfy = fl[HW + p_nxt];
            const float nrfx = fr[p_nxt], nrfy = fr[HW + p_nxt];

            #pragma unroll
            for (int c = 0; c < Cn; ++c) {
                const float topL = fmaf(lwx, tl0[c][1] - tl0[c][0], tl0[c][0]);
                const float botL = fmaf(lwx, tl1[c][1] - tl1[c][0], tl1[c][0]);
                const float sL   = fmaf(lwy, botL - topL, topL);
                const float topR = fmaf(rwx, tr0[c][1] - tr0[c][0], tr0[c][0]);
                const float botR = fmaf(rwx, tr1[c][1] - tr1[c][0], tr1[c][0]);
                const float sR   = fmaf(rwy, botR - topR, topR);
                local += fabsf(sL - g[c]) + fabsf(sR - g[c]);
            }

            lfx = nlfx; lfy = nlfy; rfx = nrfx; rfy = nrfy;
        } else {
            // keep pipeline regs coherent (never taken before last chunk)
            lfx = fl[p_nxt]; lfy = fl[HW + p_nxt];
            rfx = fr[p_nxt]; rfy = fr[HW + p_nxt];
        }
    }

    // wave(64) shuffle reduce -> LDS cross-wave -> one f64 atomic per block
    #pragma unroll
    for (int off = 32; off > 0; off >>= 1)
        local += __shfl_down(local, off, 64);

    __shared__ float wsum[4];
    const int lane = threadIdx.x & 63;
    const int wid  = threadIdx.x >> 6;
    if (lane == 0) wsum[wid] = local;
    __syncthreads();
    if (threadIdx.x == 0) {
        const float s = wsum[0] + wsum[1] + wsum[2] + wsum[3];
        atomicAdd(accum, (double)s);
    }
}

__global__ void finalize_kernel(const double* __restrict__ accum,
                                float* __restrict__ out) {
    out[0] = (float)(accum[0] / (double)NTOT);
}

extern "C" void kernel_launch(void* const* d_in, const int* in_sizes, int n_in,
                              void* d_out, int out_size, void* d_ws, size_t ws_size,
                              hipStream_t stream) {
    const float* L   = (const float*)d_in[0];
    const float* R   = (const float*)d_in[1];
    const float* flm = (const float*)d_in[2];
    const float* frm = (const float*)d_in[3];
    const float* gt  = (const float*)d_in[4];
    double* accum = (double*)d_ws;

    (void)hipMemsetAsync(accum, 0, sizeof(double), stream);
    warp_loss_kernel<<<NWG, BLK, 0, stream>>>(L, R, flm, frm, gt, accum);
    finalize_kernel<<<1, 1, 0, stream>>>(accum, (float*)d_out);
}

// Round 11
// 141.654 us; speedup vs baseline: 1.6873x; 1.1384x over previous
//
#include <hip/hip_runtime.h>

constexpr int Bn = 8, Cn = 3, Hn = 720, Wn = 1280;
constexpr int HW = Hn * Wn;                    // 921600 px per image
constexpr long long NTOT = (long long)Bn * Cn * HW;

constexpr int BLK    = 256;
constexpr int NBX    = 512;                    // blocks per XCD (= per batch image)
constexpr int NWG    = 8 * NBX;                // 4096 blocks = 16/CU (2 exact rounds of 8)
constexpr int CH     = NBX * BLK;              // 131072 px per chunk per image
constexpr int NCHUNK = (HW + CH - 1) / CH;     // 8 (7 full + 4096-px partial)

// 8B tap-pair; 4B-aligned (gfx950 handles dword-aligned dwordx2)
typedef float f2 __attribute__((ext_vector_type(2), aligned(4)));

// One gather address per row: o0 -> (y0, x0), o1 -> (y1, x0).
// x0 = min(floor(xc), W-2) keeps the 8B pair in-row; wx in [0,1] (wx=1 at border).
__device__ __forceinline__ void mk2(float xf, float yf,
                                    int& o0, int& o1, float& wx, float& wy) {
    xf = fminf(fmaxf(xf, 0.f), (float)(Wn - 1));
    yf = fminf(fmaxf(yf, 0.f), (float)(Hn - 1));
    const int x0 = min((int)floorf(xf), Wn - 2);
    wx = xf - (float)x0;
    const float y0f = floorf(yf);
    const int y0 = (int)y0f;
    const int y1 = min(y0 + 1, Hn - 1);
    wy = yf - y0f;
    o0 = y0 * Wn + x0;
    o1 = y1 * Wn + x0;
}

__global__ __launch_bounds__(256) void warp_loss_kernel(
        const float* __restrict__ L, const float* __restrict__ R,
        const float* __restrict__ Flm, const float* __restrict__ Frm,
        const float* __restrict__ G, double* __restrict__ accum) {
    // XCD k (= bid%8) owns batch image k. 512 blocks/XCD = 2 exact rounds of
    // the XCD's 256 block-slots (backfill absorbs finish-time skew).
    const int b     = blockIdx.x & 7;
    const int inner = blockIdx.x >> 3;

    const float* __restrict__ Lb = L + (size_t)b * Cn * HW;
    const float* __restrict__ Rb = R + (size_t)b * Cn * HW;
    const float* __restrict__ Gb = G + (size_t)b * Cn * HW;
    const float* __restrict__ fl = Flm + (size_t)b * 2 * HW;  // [0,HW)=x, [HW,2HW)=y
    const float* __restrict__ fr = Frm + (size_t)b * 2 * HW;

    float local = 0.f;

    const int p0 = inner * BLK + (int)threadIdx.x;   // [0, 131072)
    // software pipeline: flow for chunk 0 loaded up front (p0 < HW always)
    float lfx = fl[p0], lfy = fl[HW + p0];
    float rfx = fr[p0], rfy = fr[HW + p0];

    for (int chunk = 0; chunk < NCHUNK; ++chunk) {
        const int p = p0 + chunk * CH;               // may exceed HW on last chunk

        if (p < HW) {   // wave-uniform (p0 wave-contiguous, CH multiple of 64)
            const int p_nxt = min(p0 + (chunk + 1) * CH, HW - 1);  // clamped prefetch
            const int y = p / Wn;
            const int x = p - y * Wn;

            int   lo0, lo1, ro0, ro1;
            float lwx, lwy, rwx, rwy;
            mk2((float)x + lfx, (float)y + lfy, lo0, lo1, lwx, lwy);
            mk2((float)x + rfx, (float)y + rfy, ro0, ro1, rwx, rwy);

            // ---- issue ALL 19 loads (12 gather dwordx2 + 3 gt + 4 next-flow)
            //      before ANY consumption. sched_barrier(0) fences the
            //      scheduler from re-serializing into load->use epochs. ----
            f2 tl0[Cn], tl1[Cn], tr0[Cn], tr1[Cn];
            float g[Cn];
            #pragma unroll
            for (int c = 0; c < Cn; ++c) {
                const float* __restrict__ Lc = Lb + c * HW;
                const float* __restrict__ Rc = Rb + c * HW;
                tl0[c] = *reinterpret_cast<const f2*>(Lc + lo0);
                tl1[c] = *reinterpret_cast<const f2*>(Lc + lo1);
                tr0[c] = *reinterpret_cast<const f2*>(Rc + ro0);
                tr1[c] = *reinterpret_cast<const f2*>(Rc + ro1);
                g[c]   = Gb[c * HW + p];
            }
            const float nlfx = fl[p_nxt], nlfy = fl[HW + p_nxt];
            const float nrfx = fr[p_nxt], nrfy = fr[HW + p_nxt];

            __builtin_amdgcn_sched_barrier(0);   // loads above, math below

            #pragma unroll
            for (int c = 0; c < Cn; ++c) {
                const float topL = fmaf(lwx, tl0[c][1] - tl0[c][0], tl0[c][0]);
                const float botL = fmaf(lwx, tl1[c][1] - tl1[c][0], tl1[c][0]);
                const float sL   = fmaf(lwy, botL - topL, topL);
                const float topR = fmaf(rwx, tr0[c][1] - tr0[c][0], tr0[c][0]);
                const float botR = fmaf(rwx, tr1[c][1] - tr1[c][0], tr1[c][0]);
                const float sR   = fmaf(rwy, botR - topR, topR);
                local += fabsf(sL - g[c]) + fabsf(sR - g[c]);
            }

            lfx = nlfx; lfy = nlfy; rfx = nrfx; rfy = nrfy;
        }
    }

    // wave(64) shuffle reduce -> LDS cross-wave -> one f64 atomic per block
    #pragma unroll
    for (int off = 32; off > 0; off >>= 1)
        local += __shfl_down(local, off, 64);

    __shared__ float wsum[4];
    const int lane = threadIdx.x & 63;
    const int wid  = threadIdx.x >> 6;
    if (lane == 0) wsum[wid] = local;
    __syncthreads();
    if (threadIdx.x == 0) {
        const float s = wsum[0] + wsum[1] + wsum[2] + wsum[3];
        atomicAdd(accum, (double)s);
    }
}

__global__ void finalize_kernel(const double* __restrict__ accum,
                                float* __restrict__ out) {
    out[0] = (float)(accum[0] / (double)NTOT);
}

extern "C" void kernel_launch(void* const* d_in, const int* in_sizes, int n_in,
                              void* d_out, int out_size, void* d_ws, size_t ws_size,
                              hipStream_t stream) {
    const float* L   = (const float*)d_in[0];
    const float* R   = (const float*)d_in[1];
    const float* flm = (const float*)d_in[2];
    const float* frm = (const float*)d_in[3];
    const float* gt  = (const float*)d_in[4];
    double* accum = (double*)d_ws;

    (void)hipMemsetAsync(accum, 0, sizeof(double), stream);
    warp_loss_kernel<<<NWG, BLK, 0, stream>>>(L, R, flm, frm, gt, accum);
    finalize_kernel<<<1, 1, 0, stream>>>(accum, (float*)d_out);
}

// Round 12
// 139.683 us; speedup vs baseline: 1.7111x; 1.0141x over previous
//
#include <hip/hip_runtime.h>

constexpr int Bn = 8, Cn = 3, Hn = 720, Wn = 1280;
constexpr int HW = Hn * Wn;                    // 921600 px per image
constexpr long long NTOT = (long long)Bn * Cn * HW;

constexpr int BLK    = 256;
constexpr int NBX    = 512;                    // blocks per XCD (= per batch image)
constexpr int NWG    = 8 * NBX;                // 4096 blocks = 16/CU
constexpr int CH     = NBX * BLK;              // 131072 px per chunk per image
constexpr int NCHUNK = (HW + CH - 1) / CH;     // 8 (7 full + 4096-px partial)

// 8B tap-pair; 4B-aligned (gfx950 handles dword-aligned dwordx2)
typedef float f2 __attribute__((ext_vector_type(2), aligned(4)));

// One gather address per row: o0 -> (y0, x0), o1 -> (y1, x0).
// x0 = min(floor(xc), W-2) keeps the 8B pair in-row; wx in [0,1] (wx=1 at border).
__device__ __forceinline__ void mk2(float xf, float yf,
                                    int& o0, int& o1, float& wx, float& wy) {
    xf = fminf(fmaxf(xf, 0.f), (float)(Wn - 1));
    yf = fminf(fmaxf(yf, 0.f), (float)(Hn - 1));
    const int x0 = min((int)floorf(xf), Wn - 2);
    wx = xf - (float)x0;
    const float y0f = floorf(yf);
    const int y0 = (int)y0f;
    const int y1 = min(y0 + 1, Hn - 1);
    wy = yf - y0f;
    o0 = y0 * Wn + x0;
    o1 = y1 * Wn + x0;
}

// Volatile asm gather: mutually ordered, cannot be sunk past the waitcnt ->
// forces ALL 12 tap-pair loads in flight before any consumption (1 epoch).
#define GATHER2(dst, voff, base) \
    asm volatile("global_load_dwordx2 %0, %1, %2" \
                 : "=v"(dst) : "v"(voff), "s"(base))

__global__ __launch_bounds__(256) void warp_loss_kernel(
        const float* __restrict__ L, const float* __restrict__ R,
        const float* __restrict__ Flm, const float* __restrict__ Frm,
        const float* __restrict__ G, double* __restrict__ accum) {
    // XCD k (= bid%8) owns batch image k. 512 blocks/XCD = 2 exact rounds of
    // the XCD's 256 block-slots (backfill absorbs finish-time skew).
    const int b     = blockIdx.x & 7;
    const int inner = blockIdx.x >> 3;

    const float* __restrict__ Lb = L + (size_t)b * Cn * HW;
    const float* __restrict__ Rb = R + (size_t)b * Cn * HW;
    const float* __restrict__ Gb = G + (size_t)b * Cn * HW;
    const float* __restrict__ fl = Flm + (size_t)b * 2 * HW;  // [0,HW)=x, [HW,2HW)=y
    const float* __restrict__ fr = Frm + (size_t)b * 2 * HW;

    // uniform per-plane base pointers (SGPR pairs for the asm gathers)
    const float* const Lp[Cn] = { Lb, Lb + HW, Lb + 2 * HW };
    const float* const Rp[Cn] = { Rb, Rb + HW, Rb + 2 * HW };

    float local = 0.f;

    const int p0 = inner * BLK + (int)threadIdx.x;   // [0, 131072)
    float lfx = fl[p0], lfy = fl[HW + p0];
    float rfx = fr[p0], rfy = fr[HW + p0];

    for (int chunk = 0; chunk < NCHUNK; ++chunk) {
        const int p = p0 + chunk * CH;               // may exceed HW on last chunk

        if (p < HW) {   // wave-uniform (p0 wave-contiguous, CH multiple of 64)
            const int p_nxt = min(p0 + (chunk + 1) * CH, HW - 1);
            const int y = p / Wn;
            const int x = p - y * Wn;

            int   lo0, lo1, ro0, ro1;
            float lwx, lwy, rwx, rwy;
            mk2((float)x + lfx, (float)y + lfy, lo0, lo1, lwx, lwy);
            mk2((float)x + rfx, (float)y + rfy, ro0, ro1, rwx, rwy);

            const unsigned voL0 = (unsigned)lo0 * 4u, voL1 = (unsigned)lo1 * 4u;
            const unsigned voR0 = (unsigned)ro0 * 4u, voR1 = (unsigned)ro1 * 4u;

            // ---- 12 ordered gathers, all issued before any wait ----
            f2 tl0_0, tl0_1, tl0_2, tl1_0, tl1_1, tl1_2;
            f2 tr0_0, tr0_1, tr0_2, tr1_0, tr1_1, tr1_2;
            GATHER2(tl0_0, voL0, Lp[0]); GATHER2(tl1_0, voL1, Lp[0]);
            GATHER2(tl0_1, voL0, Lp[1]); GATHER2(tl1_1, voL1, Lp[1]);
            GATHER2(tl0_2, voL0, Lp[2]); GATHER2(tl1_2, voL1, Lp[2]);
            GATHER2(tr0_0, voR0, Rp[0]); GATHER2(tr1_0, voR0 == voR0 ? voR1 : voR1, Rp[0]);
            GATHER2(tr0_1, voR0, Rp[1]); GATHER2(tr1_1, voR1, Rp[1]);
            GATHER2(tr0_2, voR0, Rp[2]); GATHER2(tr1_2, voR1, Rp[2]);

            // gt (coalesced, cheap) + next chunk's flow prefetch
            const float g0 = Gb[p], g1 = Gb[HW + p], g2 = Gb[2 * HW + p];
            const float nlfx = fl[p_nxt], nlfy = fl[HW + p_nxt];
            const float nrfx = fr[p_nxt], nrfy = fr[HW + p_nxt];

            // drain the gather queue once, then fence the scheduler (rule #18)
            asm volatile("s_waitcnt vmcnt(0)" ::: "memory");
            __builtin_amdgcn_sched_barrier(0);

            const float topL0 = fmaf(lwx, tl0_0[1] - tl0_0[0], tl0_0[0]);
            const float botL0 = fmaf(lwx, tl1_0[1] - tl1_0[0], tl1_0[0]);
            const float topL1 = fmaf(lwx, tl0_1[1] - tl0_1[0], tl0_1[0]);
            const float botL1 = fmaf(lwx, tl1_1[1] - tl1_1[0], tl1_1[0]);
            const float topL2 = fmaf(lwx, tl0_2[1] - tl0_2[0], tl0_2[0]);
            const float botL2 = fmaf(lwx, tl1_2[1] - tl1_2[0], tl1_2[0]);
            const float topR0 = fmaf(rwx, tr0_0[1] - tr0_0[0], tr0_0[0]);
            const float botR0 = fmaf(rwx, tr1_0[1] - tr1_0[0], tr1_0[0]);
            const float topR1 = fmaf(rwx, tr0_1[1] - tr0_1[0], tr0_1[0]);
            const float botR1 = fmaf(rwx, tr1_1[1] - tr1_1[0], tr1_1[0]);
            const float topR2 = fmaf(rwx, tr0_2[1] - tr0_2[0], tr0_2[0]);
            const float botR2 = fmaf(rwx, tr1_2[1] - tr1_2[0], tr1_2[0]);

            const float sL0 = fmaf(lwy, botL0 - topL0, topL0);
            const float sL1 = fmaf(lwy, botL1 - topL1, topL1);
            const float sL2 = fmaf(lwy, botL2 - topL2, topL2);
            const float sR0 = fmaf(rwy, botR0 - topR0, topR0);
            const float sR1 = fmaf(rwy, botR1 - topR1, topR1);
            const float sR2 = fmaf(rwy, botR2 - topR2, topR2);

            local += fabsf(sL0 - g0) + fabsf(sR0 - g0);
            local += fabsf(sL1 - g1) + fabsf(sR1 - g1);
            local += fabsf(sL2 - g2) + fabsf(sR2 - g2);

            lfx = nlfx; lfy = nlfy; rfx = nrfx; rfy = nrfy;
        }
    }

    // wave(64) shuffle reduce -> LDS cross-wave -> one f64 atomic per block
    #pragma unroll
    for (int off = 32; off > 0; off >>= 1)
        local += __shfl_down(local, off, 64);

    __shared__ float wsum[4];
    const int lane = threadIdx.x & 63;
    const int wid  = threadIdx.x >> 6;
    if (lane == 0) wsum[wid] = local;
    __syncthreads();
    if (threadIdx.x == 0) {
        const float s = wsum[0] + wsum[1] + wsum[2] + wsum[3];
        atomicAdd(accum, (double)s);
    }
}

__global__ void finalize_kernel(const double* __restrict__ accum,
                                float* __restrict__ out) {
    out[0] = (float)(accum[0] / (double)NTOT);
}

extern "C" void kernel_launch(void* const* d_in, const int* in_sizes, int n_in,
                              void* d_out, int out_size, void* d_ws, size_t ws_size,
                              hipStream_t stream) {
    const float* L   = (const float*)d_in[0];
    const float* R   = (const float*)d_in[1];
    const float* flm = (const float*)d_in[2];
    const float* frm = (const float*)d_in[3];
    const float* gt  = (const float*)d_in[4];
    double* accum = (double*)d_ws;

    (void)hipMemsetAsync(accum, 0, sizeof(double), stream);
    warp_loss_kernel<<<NWG, BLK, 0, stream>>>(L, R, flm, frm, gt, accum);
    finalize_kernel<<<1, 1, 0, stream>>>(accum, (float*)d_out);
}